// Round 1
// baseline (4279.576 us; speedup 1.0000x reference)
//
#include <hip/hip_runtime.h>
#include <math.h>

typedef float f4 __attribute__((ext_vector_type(4)));

static constexpr int N = 50000;
static constexpr int E = 800000;
static constexpr int D = 128;

// --- degree histogram: deg_out[src]++ , deg_in[dst]++ (float atomics) ---
__global__ void deg_kernel(const int* __restrict__ src, const int* __restrict__ dst,
                           float* __restrict__ deg_out, float* __restrict__ deg_in) {
    int e = blockIdx.x * 256 + threadIdx.x;
    if (e < E) {
        atomicAdd(&deg_out[src[e]], 1.0f);
        atomicAdd(&deg_in[dst[e]], 1.0f);
    }
}

// --- in-place: deg -> rsqrt(max(deg,1)) ---
__global__ void norm_kernel(float* __restrict__ norm_src, float* __restrict__ norm_dst) {
    int i = blockIdx.x * 256 + threadIdx.x;
    if (i < N) {
        norm_src[i] = rsqrtf(fmaxf(norm_src[i], 1.0f));
        norm_dst[i] = rsqrtf(fmaxf(norm_dst[i], 1.0f));
    }
}

// --- hs[i] = emb[batch[i]] * norm_src[i]  (32 threads/node, float4 each) ---
__global__ void gather_kernel(const int* __restrict__ batch, const float* __restrict__ emb,
                              const float* __restrict__ norm_src, float* __restrict__ hs) {
    int gid = blockIdx.x * 256 + threadIdx.x;
    int i = gid >> 5;
    int c = (gid & 31) << 2;
    if (i < N) {
        float s = norm_src[i];
        f4 v = *(const f4*)(emb + (size_t)batch[i] * D + c);
        *(f4*)(hs + (size_t)i * D + c) = v * s;
    }
}

// --- agg[dst[e]] += hs[src[e]]  (32 threads/edge, float4 load, 4 atomics) ---
__global__ void scatter_kernel(const int* __restrict__ src, const int* __restrict__ dst,
                               const float* __restrict__ hs, float* __restrict__ agg) {
    int gid = blockIdx.x * 256 + threadIdx.x;
    int e = gid >> 5;
    int c = (gid & 31) << 2;
    if (e < E) {
        int s = src[e], d = dst[e];
        f4 v = *(const f4*)(hs + (size_t)s * D + c);
        float* o = agg + (size_t)d * D + c;
        atomicAdd(o + 0, v[0]);
        atomicAdd(o + 1, v[1]);
        atomicAdd(o + 2, v[2]);
        atomicAdd(o + 3, v[3]);
    }
}

// --- out[r] = relu(norm_dst[r] * (A[r] @ W) + b) * (post ? post[r] : 1) ---
// block = 256 threads; 64 rows/block; thread computes 4 rows x 8 cols.
__global__ __launch_bounds__(256) void gemm_kernel(
    const float* __restrict__ A, const float* __restrict__ W,
    const float* __restrict__ bias, const float* __restrict__ norm_dst,
    const float* __restrict__ post, float* __restrict__ out) {
    __shared__ float Wl[D * D];  // 64 KB
    int tid = threadIdx.x;
    for (int idx = tid * 4; idx < D * D; idx += 256 * 4)
        *(f4*)(Wl + idx) = *(const f4*)(W + idx);
    __syncthreads();

    int tx = tid & 15;            // 16 col-groups of 8
    int ty = tid >> 4;            // 16 row-groups of 4
    int c = tx * 8;
    int row0 = blockIdx.x * 64 + ty * 4;

    f4 acc0[4], acc1[4];
#pragma unroll
    for (int r = 0; r < 4; ++r) { acc0[r] = (f4)0.0f; acc1[r] = (f4)0.0f; }

    for (int k4 = 0; k4 < D / 4; ++k4) {
        f4 a[4];
#pragma unroll
        for (int r = 0; r < 4; ++r) {
            int row = row0 + r;
            a[r] = (row < N) ? *(const f4*)(A + (size_t)row * D + k4 * 4) : (f4)0.0f;
        }
#pragma unroll
        for (int kk = 0; kk < 4; ++kk) {
            int k = k4 * 4 + kk;
            f4 w0 = *(const f4*)(Wl + k * D + c);
            f4 w1 = *(const f4*)(Wl + k * D + c + 4);
#pragma unroll
            for (int r = 0; r < 4; ++r) {
                float av = a[r][kk];
                acc0[r] += av * w0;
                acc1[r] += av * w1;
            }
        }
    }

    f4 b0 = *(const f4*)(bias + c);
    f4 b1 = *(const f4*)(bias + c + 4);
#pragma unroll
    for (int r = 0; r < 4; ++r) {
        int row = row0 + r;
        if (row >= N) continue;
        float nd = norm_dst[row];
        float p = post ? post[row] : 1.0f;
        f4 o0 = acc0[r] * nd + b0;
        f4 o1 = acc1[r] * nd + b1;
#pragma unroll
        for (int j = 0; j < 4; ++j) {
            o0[j] = fmaxf(o0[j], 0.0f) * p;
            o1[j] = fmaxf(o1[j], 0.0f) * p;
        }
        *(f4*)(out + (size_t)row * D + c) = o0;
        *(f4*)(out + (size_t)row * D + c + 4) = o1;
    }
}

extern "C" void kernel_launch(void* const* d_in, const int* in_sizes, int n_in,
                              void* d_out, int out_size, void* d_ws, size_t ws_size,
                              hipStream_t stream) {
    const int*   batch = (const int*)d_in[0];
    const int*   src   = (const int*)d_in[1];
    const int*   dst   = (const int*)d_in[2];
    const float* emb   = (const float*)d_in[3];
    const float* W1    = (const float*)d_in[4];
    const float* b1    = (const float*)d_in[5];
    const float* W2    = (const float*)d_in[6];
    const float* b2    = (const float*)d_in[7];
    const float* W3    = (const float*)d_in[8];
    const float* b3    = (const float*)d_in[9];
    float* out = (float*)d_out;

    // workspace layout (floats): norm_src[N] | norm_dst[N] | hs[N*D] | agg[N*D]
    float* norm_src = (float*)d_ws;
    float* norm_dst = norm_src + N;
    float* hs       = norm_dst + N;
    float* agg      = hs + (size_t)N * D;

    hipMemsetAsync(norm_src, 0, 2 * (size_t)N * sizeof(float), stream);
    deg_kernel<<<(E + 255) / 256, 256, 0, stream>>>(src, dst, norm_src, norm_dst);
    norm_kernel<<<(N + 255) / 256, 256, 0, stream>>>(norm_src, norm_dst);
    gather_kernel<<<((size_t)N * 32 + 255) / 256, 256, 0, stream>>>(batch, emb, norm_src, hs);

    const float* Ws[3] = {W1, W2, W3};
    const float* bs[3] = {b1, b2, b3};
    for (int l = 0; l < 3; ++l) {
        hipMemsetAsync(agg, 0, (size_t)N * D * sizeof(float), stream);
        scatter_kernel<<<((size_t)E * 32 + 255) / 256, 256, 0, stream>>>(src, dst, hs, agg);
        bool last = (l == 2);
        gemm_kernel<<<(N + 63) / 64, 256, 0, stream>>>(
            agg, Ws[l], bs[l], norm_dst,
            last ? nullptr : norm_src,
            last ? out : hs);
    }
}

// Round 2
// 610.287 us; speedup vs baseline: 7.0124x; 7.0124x over previous
//
#include <hip/hip_runtime.h>
#include <math.h>

typedef float f4 __attribute__((ext_vector_type(4)));

static constexpr int N = 50000;
static constexpr int E = 800000;
static constexpr int D = 128;

// --- int degree histogram: deg_out[src]++ , deg_in[dst]++ ---
__global__ void deg_kernel(const int* __restrict__ src, const int* __restrict__ dst,
                           int* __restrict__ deg_out, int* __restrict__ deg_in) {
    int e = blockIdx.x * 256 + threadIdx.x;
    if (e < E) {
        atomicAdd(&deg_out[src[e]], 1);
        atomicAdd(&deg_in[dst[e]], 1);
    }
}

// --- norms from int degrees ---
__global__ void norm_kernel(const int* __restrict__ deg_out, const int* __restrict__ deg_in,
                            float* __restrict__ norm_src, float* __restrict__ norm_dst) {
    int i = blockIdx.x * 256 + threadIdx.x;
    if (i < N) {
        norm_src[i] = rsqrtf(fmaxf((float)deg_out[i], 1.0f));
        norm_dst[i] = rsqrtf(fmaxf((float)deg_in[i], 1.0f));
    }
}

// --- single-block exclusive scan of deg_in -> row_ptr[N+1] ---
__global__ __launch_bounds__(256) void scan_kernel(const int* __restrict__ deg,
                                                   int* __restrict__ row_ptr) {
    __shared__ int sums[256];
    int t = threadIdx.x;
    const int C = (N + 255) / 256;
    int lo = t * C, hi = min(lo + C, N);
    int s = 0;
    for (int i = lo; i < hi; ++i) s += deg[i];
    sums[t] = s;
    __syncthreads();
    for (int off = 1; off < 256; off <<= 1) {
        int v = (t >= off) ? sums[t - off] : 0;
        __syncthreads();
        sums[t] += v;
        __syncthreads();
    }
    int run = (t == 0) ? 0 : sums[t - 1];
    for (int i = lo; i < hi; ++i) {
        row_ptr[i + 1] = run + deg[i];
        run += deg[i];
    }
    if (t == 0) row_ptr[0] = 0;
}

// --- csr_src fill: for each edge, place src at row_ptr[dst] + cursor[dst]++ ---
__global__ void fill_kernel(const int* __restrict__ src, const int* __restrict__ dst,
                            const int* __restrict__ row_ptr, int* __restrict__ cursor,
                            int* __restrict__ csr_src) {
    int e = blockIdx.x * 256 + threadIdx.x;
    if (e < E) {
        int d = dst[e];
        int pos = row_ptr[d] + atomicAdd(&cursor[d], 1);
        csr_src[pos] = src[e];
    }
}

// --- hs[i] = emb[batch[i]] * norm_src[i]  (32 threads/node, float4 each) ---
__global__ void gather_kernel(const int* __restrict__ batch, const float* __restrict__ emb,
                              const float* __restrict__ norm_src, float* __restrict__ hs) {
    int gid = blockIdx.x * 256 + threadIdx.x;
    int i = gid >> 5;
    int c = (gid & 31) << 2;
    if (i < N) {
        float s = norm_src[i];
        f4 v = *(const f4*)(emb + (size_t)batch[i] * D + c);
        *(f4*)(hs + (size_t)i * D + c) = v * s;
    }
}

// --- agg[n] = sum over in-edges of hs[src]  (32 lanes/node, f4/lane, no atomics) ---
__global__ void agg_kernel(const int* __restrict__ row_ptr, const int* __restrict__ csr_src,
                           const float* __restrict__ hs, float* __restrict__ agg) {
    int gid = blockIdx.x * 256 + threadIdx.x;
    int node = gid >> 5;
    int lane = gid & 31;
    if (node >= N) return;
    int beg = row_ptr[node], end = row_ptr[node + 1];
    f4 acc0 = (f4)0.0f, acc1 = (f4)0.0f;
    int e = beg;
    for (; e + 1 < end; e += 2) {
        int s0 = csr_src[e];
        int s1 = csr_src[e + 1];
        acc0 += *(const f4*)(hs + (size_t)s0 * D + lane * 4);
        acc1 += *(const f4*)(hs + (size_t)s1 * D + lane * 4);
    }
    if (e < end) {
        int s0 = csr_src[e];
        acc0 += *(const f4*)(hs + (size_t)s0 * D + lane * 4);
    }
    *(f4*)(agg + (size_t)node * D + lane * 4) = acc0 + acc1;
}

// --- out[r] = relu(norm_dst[r] * (A[r] @ W) + b) * (post ? post[r] : 1) ---
__global__ __launch_bounds__(256) void gemm_kernel(
    const float* __restrict__ A, const float* __restrict__ W,
    const float* __restrict__ bias, const float* __restrict__ norm_dst,
    const float* __restrict__ post, float* __restrict__ out) {
    __shared__ float Wl[D * D];  // 64 KB
    int tid = threadIdx.x;
    for (int idx = tid * 4; idx < D * D; idx += 256 * 4)
        *(f4*)(Wl + idx) = *(const f4*)(W + idx);
    __syncthreads();

    int tx = tid & 15;
    int ty = tid >> 4;
    int c = tx * 8;
    int row0 = blockIdx.x * 64 + ty * 4;

    f4 acc0[4], acc1[4];
#pragma unroll
    for (int r = 0; r < 4; ++r) { acc0[r] = (f4)0.0f; acc1[r] = (f4)0.0f; }

    for (int k4 = 0; k4 < D / 4; ++k4) {
        f4 a[4];
#pragma unroll
        for (int r = 0; r < 4; ++r) {
            int row = row0 + r;
            a[r] = (row < N) ? *(const f4*)(A + (size_t)row * D + k4 * 4) : (f4)0.0f;
        }
#pragma unroll
        for (int kk = 0; kk < 4; ++kk) {
            int k = k4 * 4 + kk;
            f4 w0 = *(const f4*)(Wl + k * D + c);
            f4 w1 = *(const f4*)(Wl + k * D + c + 4);
#pragma unroll
            for (int r = 0; r < 4; ++r) {
                float av = a[r][kk];
                acc0[r] += av * w0;
                acc1[r] += av * w1;
            }
        }
    }

    f4 b0 = *(const f4*)(bias + c);
    f4 b1 = *(const f4*)(bias + c + 4);
#pragma unroll
    for (int r = 0; r < 4; ++r) {
        int row = row0 + r;
        if (row >= N) continue;
        float nd = norm_dst[row];
        float p = post ? post[row] : 1.0f;
        f4 o0 = acc0[r] * nd + b0;
        f4 o1 = acc1[r] * nd + b1;
#pragma unroll
        for (int j = 0; j < 4; ++j) {
            o0[j] = fmaxf(o0[j], 0.0f) * p;
            o1[j] = fmaxf(o1[j], 0.0f) * p;
        }
        *(f4*)(out + (size_t)row * D + c) = o0;
        *(f4*)(out + (size_t)row * D + c + 4) = o1;
    }
}

extern "C" void kernel_launch(void* const* d_in, const int* in_sizes, int n_in,
                              void* d_out, int out_size, void* d_ws, size_t ws_size,
                              hipStream_t stream) {
    const int*   batch = (const int*)d_in[0];
    const int*   src   = (const int*)d_in[1];
    const int*   dst   = (const int*)d_in[2];
    const float* emb   = (const float*)d_in[3];
    const float* W1    = (const float*)d_in[4];
    const float* b1    = (const float*)d_in[5];
    const float* W2    = (const float*)d_in[6];
    const float* b2    = (const float*)d_in[7];
    const float* W3    = (const float*)d_in[8];
    const float* b3    = (const float*)d_in[9];
    float* out = (float*)d_out;

    // ws layout (4B elems): norm_src[N] | norm_dst[N] | row_ptr[N+1] | csr_src[E]
    //                       | hs[N*D] | agg[N*D]
    // transient ints (deg_out, deg_in, cursor) alias the agg region (unused until layers).
    float* norm_src = (float*)d_ws;
    float* norm_dst = norm_src + N;
    int*   row_ptr  = (int*)(norm_dst + N);
    int*   csr_src  = row_ptr + (N + 1);
    float* hs       = (float*)(csr_src + E) + 3;  // keep 16B alignment
    float* agg      = hs + (size_t)N * D;
    int*   deg_out  = (int*)agg;   // transient, inside agg region
    int*   deg_in   = deg_out + N;
    int*   cursor   = deg_in + N;

    hipMemsetAsync(deg_out, 0, 3 * (size_t)N * sizeof(int), stream);
    deg_kernel<<<(E + 255) / 256, 256, 0, stream>>>(src, dst, deg_out, deg_in);
    norm_kernel<<<(N + 255) / 256, 256, 0, stream>>>(deg_out, deg_in, norm_src, norm_dst);
    scan_kernel<<<1, 256, 0, stream>>>(deg_in, row_ptr);
    fill_kernel<<<(E + 255) / 256, 256, 0, stream>>>(src, dst, row_ptr, cursor, csr_src);
    gather_kernel<<<((size_t)N * 32 + 255) / 256, 256, 0, stream>>>(batch, emb, norm_src, hs);

    const float* Ws[3] = {W1, W2, W3};
    const float* bs[3] = {b1, b2, b3};
    for (int l = 0; l < 3; ++l) {
        bool last = (l == 2);
        agg_kernel<<<((size_t)N * 32 + 255) / 256, 256, 0, stream>>>(row_ptr, csr_src, hs, agg);
        gemm_kernel<<<(N + 63) / 64, 256, 0, stream>>>(
            agg, Ws[l], bs[l], norm_dst,
            last ? nullptr : norm_src,
            last ? out : hs);
    }
}

// Round 3
// 521.243 us; speedup vs baseline: 8.2103x; 1.1708x over previous
//
#include <hip/hip_runtime.h>
#include <math.h>

typedef float f4 __attribute__((ext_vector_type(4)));

static constexpr int N = 50000;
static constexpr int E = 800000;
static constexpr int D = 128;
static constexpr int SCAN_NB = (N + 255) / 256;  // 196

// --- int degree histogram: deg_out[src]++ , deg_in[dst]++ ---
__global__ void deg_kernel(const int* __restrict__ src, const int* __restrict__ dst,
                           int* __restrict__ deg_out, int* __restrict__ deg_in) {
    int e = blockIdx.x * 256 + threadIdx.x;
    if (e < E) {
        atomicAdd(&deg_out[src[e]], 1);
        atomicAdd(&deg_in[dst[e]], 1);
    }
}

// --- norms from int degrees ---
__global__ void norm_kernel(const int* __restrict__ deg_out, const int* __restrict__ deg_in,
                            float* __restrict__ norm_src, float* __restrict__ norm_dst) {
    int i = blockIdx.x * 256 + threadIdx.x;
    if (i < N) {
        norm_src[i] = rsqrtf(fmaxf((float)deg_out[i], 1.0f));
        norm_dst[i] = rsqrtf(fmaxf((float)deg_in[i], 1.0f));
    }
}

// --- scan pass 1: per-block (256 elems) sums ---
__global__ __launch_bounds__(256) void scan_bsum_kernel(const int* __restrict__ deg,
                                                        int* __restrict__ bsums) {
    int i = blockIdx.x * 256 + threadIdx.x;
    int v = (i < N) ? deg[i] : 0;
#pragma unroll
    for (int off = 1; off < 64; off <<= 1) v += __shfl_xor(v, off, 64);
    __shared__ int ws[4];
    if ((threadIdx.x & 63) == 0) ws[threadIdx.x >> 6] = v;
    __syncthreads();
    if (threadIdx.x == 0) bsums[blockIdx.x] = ws[0] + ws[1] + ws[2] + ws[3];
}

// --- scan pass 2: exclusive scan of block sums (1 block) ---
__global__ __launch_bounds__(256) void scan_bsums_kernel(int* __restrict__ bsums) {
    __shared__ int s[256];
    int t = threadIdx.x;
    s[t] = (t < SCAN_NB) ? bsums[t] : 0;
    __syncthreads();
    for (int off = 1; off < 256; off <<= 1) {
        int v = (t >= off) ? s[t - off] : 0;
        __syncthreads();
        s[t] += v;
        __syncthreads();
    }
    if (t < SCAN_NB) bsums[t] = (t == 0) ? 0 : s[t - 1];
}

// --- scan pass 3: per-block inclusive rescan + block offset -> row_ptr ---
__global__ __launch_bounds__(256) void scan_final_kernel(const int* __restrict__ deg,
                                                         const int* __restrict__ bsums,
                                                         int* __restrict__ row_ptr) {
    __shared__ int s[256];
    int b = blockIdx.x, t = threadIdx.x;
    int i = b * 256 + t;
    s[t] = (i < N) ? deg[i] : 0;
    __syncthreads();
    for (int off = 1; off < 256; off <<= 1) {
        int v = (t >= off) ? s[t - off] : 0;
        __syncthreads();
        s[t] += v;
        __syncthreads();
    }
    if (i < N) row_ptr[i + 1] = s[t] + bsums[b];
    if (i == 0) row_ptr[0] = 0;
}

// --- csr_src fill ---
__global__ void fill_kernel(const int* __restrict__ src, const int* __restrict__ dst,
                            const int* __restrict__ row_ptr, int* __restrict__ cursor,
                            int* __restrict__ csr_src) {
    int e = blockIdx.x * 256 + threadIdx.x;
    if (e < E) {
        int d = dst[e];
        int pos = row_ptr[d] + atomicAdd(&cursor[d], 1);
        csr_src[pos] = src[e];
    }
}

// --- hs[i] = emb[batch[i]] * norm_src[i] ---
__global__ void gather_kernel(const int* __restrict__ batch, const float* __restrict__ emb,
                              const float* __restrict__ norm_src, float* __restrict__ hs) {
    int gid = blockIdx.x * 256 + threadIdx.x;
    int i = gid >> 5;
    int c = (gid & 31) << 2;
    if (i < N) {
        float s = norm_src[i];
        f4 v = *(const f4*)(emb + (size_t)batch[i] * D + c);
        *(f4*)(hs + (size_t)i * D + c) = v * s;
    }
}

// --- agg[n] = sum of hs[src] over in-edges; 1 wave/node, 2 edge-groups x 4 unroll ---
__global__ void agg_kernel(const int* __restrict__ row_ptr, const int* __restrict__ csr_src,
                           const float* __restrict__ hs, float* __restrict__ agg) {
    int gid = blockIdx.x * 256 + threadIdx.x;
    int node = gid >> 6;
    if (node >= N) return;
    int lane = threadIdx.x & 63;
    int grp = lane >> 5;           // edge group 0/1
    int col = (lane & 31) << 2;    // float4 column slice
    int beg = row_ptr[node], end = row_ptr[node + 1];

    f4 a0 = (f4)0.0f, a1 = (f4)0.0f, a2 = (f4)0.0f, a3 = (f4)0.0f;
    int e = beg + grp;
    for (; e + 6 < end; e += 8) {
        int s0 = csr_src[e];
        int s1 = csr_src[e + 2];
        int s2 = csr_src[e + 4];
        int s3 = csr_src[e + 6];
        a0 += *(const f4*)(hs + (size_t)s0 * D + col);
        a1 += *(const f4*)(hs + (size_t)s1 * D + col);
        a2 += *(const f4*)(hs + (size_t)s2 * D + col);
        a3 += *(const f4*)(hs + (size_t)s3 * D + col);
    }
    for (; e < end; e += 2)
        a0 += *(const f4*)(hs + (size_t)csr_src[e] * D + col);
    a0 += a1;
    a2 += a3;
    a0 += a2;

    f4 o;
#pragma unroll
    for (int j = 0; j < 4; ++j)
        o[j] = a0[j] + __shfl_xor(a0[j], 32, 64);
    if (grp == 0)
        *(f4*)(agg + (size_t)node * D + col) = o;
}

// --- out[r] = relu(norm_dst[r] * (A[r] @ W) + b) * (post ? post[r] : 1) ---
__global__ __launch_bounds__(256) void gemm_kernel(
    const float* __restrict__ A, const float* __restrict__ W,
    const float* __restrict__ bias, const float* __restrict__ norm_dst,
    const float* __restrict__ post, float* __restrict__ out) {
    __shared__ float Wl[D * D];  // 64 KB
    int tid = threadIdx.x;
    for (int idx = tid * 4; idx < D * D; idx += 256 * 4)
        *(f4*)(Wl + idx) = *(const f4*)(W + idx);
    __syncthreads();

    int tx = tid & 15;
    int ty = tid >> 4;
    int c = tx * 8;
    int row0 = blockIdx.x * 64 + ty * 4;

    f4 acc0[4], acc1[4];
#pragma unroll
    for (int r = 0; r < 4; ++r) { acc0[r] = (f4)0.0f; acc1[r] = (f4)0.0f; }

    for (int k4 = 0; k4 < D / 4; ++k4) {
        f4 a[4];
#pragma unroll
        for (int r = 0; r < 4; ++r) {
            int row = row0 + r;
            a[r] = (row < N) ? *(const f4*)(A + (size_t)row * D + k4 * 4) : (f4)0.0f;
        }
#pragma unroll
        for (int kk = 0; kk < 4; ++kk) {
            int k = k4 * 4 + kk;
            f4 w0 = *(const f4*)(Wl + k * D + c);
            f4 w1 = *(const f4*)(Wl + k * D + c + 4);
#pragma unroll
            for (int r = 0; r < 4; ++r) {
                float av = a[r][kk];
                acc0[r] += av * w0;
                acc1[r] += av * w1;
            }
        }
    }

    f4 b0 = *(const f4*)(bias + c);
    f4 b1 = *(const f4*)(bias + c + 4);
#pragma unroll
    for (int r = 0; r < 4; ++r) {
        int row = row0 + r;
        if (row >= N) continue;
        float nd = norm_dst[row];
        float p = post ? post[row] : 1.0f;
        f4 o0 = acc0[r] * nd + b0;
        f4 o1 = acc1[r] * nd + b1;
#pragma unroll
        for (int j = 0; j < 4; ++j) {
            o0[j] = fmaxf(o0[j], 0.0f) * p;
            o1[j] = fmaxf(o1[j], 0.0f) * p;
        }
        *(f4*)(out + (size_t)row * D + c) = o0;
        *(f4*)(out + (size_t)row * D + c + 4) = o1;
    }
}

extern "C" void kernel_launch(void* const* d_in, const int* in_sizes, int n_in,
                              void* d_out, int out_size, void* d_ws, size_t ws_size,
                              hipStream_t stream) {
    const int*   batch = (const int*)d_in[0];
    const int*   src   = (const int*)d_in[1];
    const int*   dst   = (const int*)d_in[2];
    const float* emb   = (const float*)d_in[3];
    const float* W1    = (const float*)d_in[4];
    const float* b1    = (const float*)d_in[5];
    const float* W2    = (const float*)d_in[6];
    const float* b2    = (const float*)d_in[7];
    const float* W3    = (const float*)d_in[8];
    const float* b3    = (const float*)d_in[9];
    float* out = (float*)d_out;

    // ws layout (4B elems): norm_src[N] | norm_dst[N] | row_ptr[N+1] | csr_src[E]
    //                       | hs[N*D] | agg[N*D]
    // transient ints (deg_out, deg_in, cursor, bsums) alias the agg region.
    float* norm_src = (float*)d_ws;
    float* norm_dst = norm_src + N;
    int*   row_ptr  = (int*)(norm_dst + N);
    int*   csr_src  = row_ptr + (N + 1);
    float* hs       = (float*)(csr_src + E) + 3;  // 16B alignment
    float* agg      = hs + (size_t)N * D;
    int*   deg_out  = (int*)agg;   // transient
    int*   deg_in   = deg_out + N;
    int*   cursor   = deg_in + N;
    int*   bsums    = cursor + N;

    hipMemsetAsync(deg_out, 0, 3 * (size_t)N * sizeof(int), stream);
    deg_kernel<<<(E + 255) / 256, 256, 0, stream>>>(src, dst, deg_out, deg_in);
    norm_kernel<<<(N + 255) / 256, 256, 0, stream>>>(deg_out, deg_in, norm_src, norm_dst);
    scan_bsum_kernel<<<SCAN_NB, 256, 0, stream>>>(deg_in, bsums);
    scan_bsums_kernel<<<1, 256, 0, stream>>>(bsums);
    scan_final_kernel<<<SCAN_NB, 256, 0, stream>>>(deg_in, bsums, row_ptr);
    fill_kernel<<<(E + 255) / 256, 256, 0, stream>>>(src, dst, row_ptr, cursor, csr_src);
    gather_kernel<<<((size_t)N * 32 + 255) / 256, 256, 0, stream>>>(batch, emb, norm_src, hs);

    const float* Ws[3] = {W1, W2, W3};
    const float* bs[3] = {b1, b2, b3};
    for (int l = 0; l < 3; ++l) {
        bool last = (l == 2);
        agg_kernel<<<((size_t)N * 64 + 255) / 256, 256, 0, stream>>>(row_ptr, csr_src, hs, agg);
        gemm_kernel<<<(N + 63) / 64, 256, 0, stream>>>(
            agg, Ws[l], bs[l], norm_dst,
            last ? nullptr : norm_src,
            last ? out : hs);
    }
}

// Round 4
// 507.815 us; speedup vs baseline: 8.4274x; 1.0264x over previous
//
#include <hip/hip_runtime.h>
#include <math.h>

typedef float f4 __attribute__((ext_vector_type(4)));

static constexpr int N = 50000;
static constexpr int E = 800000;
static constexpr int D = 128;
static constexpr int SCAN_NB = (N + 255) / 256;  // 196
static constexpr int GEMM_RB = (N + 255) / 256;  // 196 row blocks (256 rows each)

// --- int degree histogram: deg_out[src]++ , deg_in[dst]++ ---
__global__ void deg_kernel(const int* __restrict__ src, const int* __restrict__ dst,
                           int* __restrict__ deg_out, int* __restrict__ deg_in) {
    int e = blockIdx.x * 256 + threadIdx.x;
    if (e < E) {
        atomicAdd(&deg_out[src[e]], 1);
        atomicAdd(&deg_in[dst[e]], 1);
    }
}

// --- norms from int degrees ---
__global__ void norm_kernel(const int* __restrict__ deg_out, const int* __restrict__ deg_in,
                            float* __restrict__ norm_src, float* __restrict__ norm_dst) {
    int i = blockIdx.x * 256 + threadIdx.x;
    if (i < N) {
        norm_src[i] = rsqrtf(fmaxf((float)deg_out[i], 1.0f));
        norm_dst[i] = rsqrtf(fmaxf((float)deg_in[i], 1.0f));
    }
}

// --- scan pass 1: per-block (256 elems) sums ---
__global__ __launch_bounds__(256) void scan_bsum_kernel(const int* __restrict__ deg,
                                                        int* __restrict__ bsums) {
    int i = blockIdx.x * 256 + threadIdx.x;
    int v = (i < N) ? deg[i] : 0;
#pragma unroll
    for (int off = 1; off < 64; off <<= 1) v += __shfl_xor(v, off, 64);
    __shared__ int ws[4];
    if ((threadIdx.x & 63) == 0) ws[threadIdx.x >> 6] = v;
    __syncthreads();
    if (threadIdx.x == 0) bsums[blockIdx.x] = ws[0] + ws[1] + ws[2] + ws[3];
}

// --- scan pass 2: exclusive scan of block sums (1 block) ---
__global__ __launch_bounds__(256) void scan_bsums_kernel(int* __restrict__ bsums) {
    __shared__ int s[256];
    int t = threadIdx.x;
    s[t] = (t < SCAN_NB) ? bsums[t] : 0;
    __syncthreads();
    for (int off = 1; off < 256; off <<= 1) {
        int v = (t >= off) ? s[t - off] : 0;
        __syncthreads();
        s[t] += v;
        __syncthreads();
    }
    if (t < SCAN_NB) bsums[t] = (t == 0) ? 0 : s[t - 1];
}

// --- scan pass 3: per-block inclusive rescan + block offset -> row_ptr ---
__global__ __launch_bounds__(256) void scan_final_kernel(const int* __restrict__ deg,
                                                         const int* __restrict__ bsums,
                                                         int* __restrict__ row_ptr) {
    __shared__ int s[256];
    int b = blockIdx.x, t = threadIdx.x;
    int i = b * 256 + t;
    s[t] = (i < N) ? deg[i] : 0;
    __syncthreads();
    for (int off = 1; off < 256; off <<= 1) {
        int v = (t >= off) ? s[t - off] : 0;
        __syncthreads();
        s[t] += v;
        __syncthreads();
    }
    if (i < N) row_ptr[i + 1] = s[t] + bsums[b];
    if (i == 0) row_ptr[0] = 0;
}

// --- csr_src fill ---
__global__ void fill_kernel(const int* __restrict__ src, const int* __restrict__ dst,
                            const int* __restrict__ row_ptr, int* __restrict__ cursor,
                            int* __restrict__ csr_src) {
    int e = blockIdx.x * 256 + threadIdx.x;
    if (e < E) {
        int d = dst[e];
        int pos = row_ptr[d] + atomicAdd(&cursor[d], 1);
        csr_src[pos] = src[e];
    }
}

// --- hs[i] = emb[batch[i]] * norm_src[i] ---
__global__ void gather_kernel(const int* __restrict__ batch, const float* __restrict__ emb,
                              const float* __restrict__ norm_src, float* __restrict__ hs) {
    int gid = blockIdx.x * 256 + threadIdx.x;
    int i = gid >> 5;
    int c = (gid & 31) << 2;
    if (i < N) {
        float s = norm_src[i];
        f4 v = *(const f4*)(emb + (size_t)batch[i] * D + c);
        *(f4*)(hs + (size_t)i * D + c) = v * s;
    }
}

// --- agg[n] = sum of hs[src]; 1 wave/node, 2 edge-groups x 8-deep unroll ---
__global__ void agg_kernel(const int* __restrict__ row_ptr, const int* __restrict__ csr_src,
                           const float* __restrict__ hs, float* __restrict__ agg) {
    int gid = blockIdx.x * 256 + threadIdx.x;
    int node = gid >> 6;
    if (node >= N) return;
    int lane = threadIdx.x & 63;
    int grp = lane >> 5;           // edge group 0/1
    int col = (lane & 31) << 2;    // float4 column slice
    int beg = row_ptr[node], end = row_ptr[node + 1];

    f4 a0 = (f4)0.0f, a1 = (f4)0.0f, a2 = (f4)0.0f, a3 = (f4)0.0f;
    f4 a4 = (f4)0.0f, a5 = (f4)0.0f, a6 = (f4)0.0f, a7 = (f4)0.0f;
    int e = beg + grp;
    for (; e + 14 < end; e += 16) {
        int s0 = csr_src[e];
        int s1 = csr_src[e + 2];
        int s2 = csr_src[e + 4];
        int s3 = csr_src[e + 6];
        int s4 = csr_src[e + 8];
        int s5 = csr_src[e + 10];
        int s6 = csr_src[e + 12];
        int s7 = csr_src[e + 14];
        a0 += *(const f4*)(hs + (size_t)s0 * D + col);
        a1 += *(const f4*)(hs + (size_t)s1 * D + col);
        a2 += *(const f4*)(hs + (size_t)s2 * D + col);
        a3 += *(const f4*)(hs + (size_t)s3 * D + col);
        a4 += *(const f4*)(hs + (size_t)s4 * D + col);
        a5 += *(const f4*)(hs + (size_t)s5 * D + col);
        a6 += *(const f4*)(hs + (size_t)s6 * D + col);
        a7 += *(const f4*)(hs + (size_t)s7 * D + col);
    }
    for (; e < end; e += 2)
        a0 += *(const f4*)(hs + (size_t)csr_src[e] * D + col);
    a0 += a1; a2 += a3; a4 += a5; a6 += a7;
    a0 += a2; a4 += a6;
    a0 += a4;

    f4 o;
#pragma unroll
    for (int j = 0; j < 4; ++j)
        o[j] = a0[j] + __shfl_xor(a0[j], 32, 64);
    if (grp == 0)
        *(f4*)(agg + (size_t)node * D + col) = o;
}

// --- out[r, cb*64 + :64] = relu(norm_dst[r]*(A[r] @ W[:, cb*64:+64]) + b) * post ---
// block: 256 threads, 256 rows x 64 cols; thread: 8 rows x 8 cols (two f4).
// Wl = 128x64 = 32 KB -> 5 blocks/CU. Cols at tx*4 and tx*4+32: conflict-free.
__global__ __launch_bounds__(256, 4) void gemm_kernel(
    const float* __restrict__ A, const float* __restrict__ W,
    const float* __restrict__ bias, const float* __restrict__ norm_dst,
    const float* __restrict__ post, float* __restrict__ out) {
    __shared__ float Wl[D * 64];  // 32 KB
    int tid = threadIdx.x;
    int cb = blockIdx.y;          // column half: cols [cb*64, cb*64+64)
#pragma unroll
    for (int it = 0; it < 8; ++it) {
        int i = tid + it * 256;   // f4 index into Wl
        int k = i >> 4;
        int c4 = i & 15;
        *(f4*)(Wl + i * 4) = *(const f4*)(W + (size_t)k * D + cb * 64 + c4 * 4);
    }
    __syncthreads();

    int tx = tid & 7;             // 8 col groups
    int ty = tid >> 3;            // 32 row groups of 8
    int c = tx * 4;               // first f4 col (second at c+32)
    int row0 = blockIdx.x * 256 + ty * 8;

    int rowi[8];
    const float* ap[8];
#pragma unroll
    for (int r = 0; r < 8; ++r) {
        rowi[r] = row0 + r;
        int rc = rowi[r] < N ? rowi[r] : (N - 1);
        ap[r] = A + (size_t)rc * D;
    }

    f4 acc0[8], acc1[8];
#pragma unroll
    for (int r = 0; r < 8; ++r) { acc0[r] = (f4)0.0f; acc1[r] = (f4)0.0f; }

    for (int k4 = 0; k4 < D / 4; ++k4) {
        f4 a[8];
#pragma unroll
        for (int r = 0; r < 8; ++r)
            a[r] = *(const f4*)(ap[r] + k4 * 4);
#pragma unroll
        for (int kk = 0; kk < 4; ++kk) {
            int k = k4 * 4 + kk;
            f4 w0 = *(const f4*)(Wl + k * 64 + c);
            f4 w1 = *(const f4*)(Wl + k * 64 + c + 32);
#pragma unroll
            for (int r = 0; r < 8; ++r) {
                float av = a[r][kk];
                acc0[r] += av * w0;
                acc1[r] += av * w1;
            }
        }
    }

    f4 b0 = *(const f4*)(bias + cb * 64 + c);
    f4 b1 = *(const f4*)(bias + cb * 64 + c + 32);
#pragma unroll
    for (int r = 0; r < 8; ++r) {
        int row = rowi[r];
        if (row >= N) continue;
        float nd = norm_dst[row];
        float p = post ? post[row] : 1.0f;
        f4 o0 = acc0[r] * nd + b0;
        f4 o1 = acc1[r] * nd + b1;
#pragma unroll
        for (int j = 0; j < 4; ++j) {
            o0[j] = fmaxf(o0[j], 0.0f) * p;
            o1[j] = fmaxf(o1[j], 0.0f) * p;
        }
        *(f4*)(out + (size_t)row * D + cb * 64 + c) = o0;
        *(f4*)(out + (size_t)row * D + cb * 64 + c + 32) = o1;
    }
}

extern "C" void kernel_launch(void* const* d_in, const int* in_sizes, int n_in,
                              void* d_out, int out_size, void* d_ws, size_t ws_size,
                              hipStream_t stream) {
    const int*   batch = (const int*)d_in[0];
    const int*   src   = (const int*)d_in[1];
    const int*   dst   = (const int*)d_in[2];
    const float* emb   = (const float*)d_in[3];
    const float* W1    = (const float*)d_in[4];
    const float* b1    = (const float*)d_in[5];
    const float* W2    = (const float*)d_in[6];
    const float* b2    = (const float*)d_in[7];
    const float* W3    = (const float*)d_in[8];
    const float* b3    = (const float*)d_in[9];
    float* out = (float*)d_out;

    // ws layout (4B elems): norm_src[N] | norm_dst[N] | row_ptr[N+1] | csr_src[E]
    //                       | hs[N*D] | agg[N*D]
    // transient ints (deg_out, deg_in, cursor, bsums) alias the agg region.
    float* norm_src = (float*)d_ws;
    float* norm_dst = norm_src + N;
    int*   row_ptr  = (int*)(norm_dst + N);
    int*   csr_src  = row_ptr + (N + 1);
    float* hs       = (float*)(csr_src + E) + 3;  // 16B alignment
    float* agg      = hs + (size_t)N * D;
    int*   deg_out  = (int*)agg;   // transient
    int*   deg_in   = deg_out + N;
    int*   cursor   = deg_in + N;
    int*   bsums    = cursor + N;

    hipMemsetAsync(deg_out, 0, 3 * (size_t)N * sizeof(int), stream);
    deg_kernel<<<(E + 255) / 256, 256, 0, stream>>>(src, dst, deg_out, deg_in);
    norm_kernel<<<(N + 255) / 256, 256, 0, stream>>>(deg_out, deg_in, norm_src, norm_dst);
    scan_bsum_kernel<<<SCAN_NB, 256, 0, stream>>>(deg_in, bsums);
    scan_bsums_kernel<<<1, 256, 0, stream>>>(bsums);
    scan_final_kernel<<<SCAN_NB, 256, 0, stream>>>(deg_in, bsums, row_ptr);
    fill_kernel<<<(E + 255) / 256, 256, 0, stream>>>(src, dst, row_ptr, cursor, csr_src);
    gather_kernel<<<((size_t)N * 32 + 255) / 256, 256, 0, stream>>>(batch, emb, norm_src, hs);

    const float* Ws[3] = {W1, W2, W3};
    const float* bs[3] = {b1, b2, b3};
    dim3 ggrid(GEMM_RB, 2);
    for (int l = 0; l < 3; ++l) {
        bool last = (l == 2);
        agg_kernel<<<((size_t)N * 64 + 255) / 256, 256, 0, stream>>>(row_ptr, csr_src, hs, agg);
        gemm_kernel<<<ggrid, 256, 0, stream>>>(
            agg, Ws[l], bs[l], norm_dst,
            last ? nullptr : norm_src,
            last ? out : hs);
    }
}

// Round 5
// 488.846 us; speedup vs baseline: 8.7544x; 1.0388x over previous
//
#include <hip/hip_runtime.h>
#include <math.h>

typedef float f4 __attribute__((ext_vector_type(4)));

static constexpr int N = 50000;
static constexpr int E = 800000;
static constexpr int D = 128;
static constexpr int SCAN_NB = (N + 255) / 256;   // 196
static constexpr int GEMM_RB = (N + 255) / 256;   // 196 row blocks (256 rows each)
static constexpr int N_PAD = GEMM_RB * 256;       // 50176 padded rows

// --- int degree histogram: deg_out[src]++ , deg_in[dst]++ ---
__global__ void deg_kernel(const int* __restrict__ src, const int* __restrict__ dst,
                           int* __restrict__ deg_out, int* __restrict__ deg_in) {
    int e = blockIdx.x * 256 + threadIdx.x;
    if (e < E) {
        atomicAdd(&deg_out[src[e]], 1);
        atomicAdd(&deg_in[dst[e]], 1);
    }
}

// --- norms from int degrees ---
__global__ void norm_kernel(const int* __restrict__ deg_out, const int* __restrict__ deg_in,
                            float* __restrict__ norm_src, float* __restrict__ norm_dst) {
    int i = blockIdx.x * 256 + threadIdx.x;
    if (i < N) {
        norm_src[i] = rsqrtf(fmaxf((float)deg_out[i], 1.0f));
        norm_dst[i] = rsqrtf(fmaxf((float)deg_in[i], 1.0f));
    }
}

// --- scan pass 1: per-block (256 elems) sums ---
__global__ __launch_bounds__(256) void scan_bsum_kernel(const int* __restrict__ deg,
                                                        int* __restrict__ bsums) {
    int i = blockIdx.x * 256 + threadIdx.x;
    int v = (i < N) ? deg[i] : 0;
#pragma unroll
    for (int off = 1; off < 64; off <<= 1) v += __shfl_xor(v, off, 64);
    __shared__ int ws[4];
    if ((threadIdx.x & 63) == 0) ws[threadIdx.x >> 6] = v;
    __syncthreads();
    if (threadIdx.x == 0) bsums[blockIdx.x] = ws[0] + ws[1] + ws[2] + ws[3];
}

// --- scan pass 2: exclusive scan of block sums (1 block) ---
__global__ __launch_bounds__(256) void scan_bsums_kernel(int* __restrict__ bsums) {
    __shared__ int s[256];
    int t = threadIdx.x;
    s[t] = (t < SCAN_NB) ? bsums[t] : 0;
    __syncthreads();
    for (int off = 1; off < 256; off <<= 1) {
        int v = (t >= off) ? s[t - off] : 0;
        __syncthreads();
        s[t] += v;
        __syncthreads();
    }
    if (t < SCAN_NB) bsums[t] = (t == 0) ? 0 : s[t - 1];
}

// --- scan pass 3: per-block inclusive rescan + block offset -> row_ptr ---
__global__ __launch_bounds__(256) void scan_final_kernel(const int* __restrict__ deg,
                                                         const int* __restrict__ bsums,
                                                         int* __restrict__ row_ptr) {
    __shared__ int s[256];
    int b = blockIdx.x, t = threadIdx.x;
    int i = b * 256 + t;
    s[t] = (i < N) ? deg[i] : 0;
    __syncthreads();
    for (int off = 1; off < 256; off <<= 1) {
        int v = (t >= off) ? s[t - off] : 0;
        __syncthreads();
        s[t] += v;
        __syncthreads();
    }
    if (i < N) row_ptr[i + 1] = s[t] + bsums[b];
    if (i == 0) row_ptr[0] = 0;
}

// --- csr_src fill ---
__global__ void fill_kernel(const int* __restrict__ src, const int* __restrict__ dst,
                            const int* __restrict__ row_ptr, int* __restrict__ cursor,
                            int* __restrict__ csr_src) {
    int e = blockIdx.x * 256 + threadIdx.x;
    if (e < E) {
        int d = dst[e];
        int pos = row_ptr[d] + atomicAdd(&cursor[d], 1);
        csr_src[pos] = src[e];
    }
}

// --- hs[i] = emb[batch[i]] * norm_src[i] ---
__global__ void gather_kernel(const int* __restrict__ batch, const float* __restrict__ emb,
                              const float* __restrict__ norm_src, float* __restrict__ hs) {
    int gid = blockIdx.x * 256 + threadIdx.x;
    int i = gid >> 5;
    int c = (gid & 31) << 2;
    if (i < N) {
        float s = norm_src[i];
        f4 v = *(const f4*)(emb + (size_t)batch[i] * D + c);
        *(f4*)(hs + (size_t)i * D + c) = v * s;
    }
}

// --- agg[n] = sum of hs[src]; 1 wave/node, 2 edge-groups x 8-deep unroll ---
__global__ void agg_kernel(const int* __restrict__ row_ptr, const int* __restrict__ csr_src,
                           const float* __restrict__ hs, float* __restrict__ agg) {
    int gid = blockIdx.x * 256 + threadIdx.x;
    int node = gid >> 6;
    if (node >= N) return;
    int lane = threadIdx.x & 63;
    int grp = lane >> 5;           // edge group 0/1
    int col = (lane & 31) << 2;    // float4 column slice
    int beg = row_ptr[node], end = row_ptr[node + 1];

    f4 a0 = (f4)0.0f, a1 = (f4)0.0f, a2 = (f4)0.0f, a3 = (f4)0.0f;
    f4 a4 = (f4)0.0f, a5 = (f4)0.0f, a6 = (f4)0.0f, a7 = (f4)0.0f;
    int e = beg + grp;
    for (; e + 14 < end; e += 16) {
        int s0 = csr_src[e];
        int s1 = csr_src[e + 2];
        int s2 = csr_src[e + 4];
        int s3 = csr_src[e + 6];
        int s4 = csr_src[e + 8];
        int s5 = csr_src[e + 10];
        int s6 = csr_src[e + 12];
        int s7 = csr_src[e + 14];
        a0 += *(const f4*)(hs + (size_t)s0 * D + col);
        a1 += *(const f4*)(hs + (size_t)s1 * D + col);
        a2 += *(const f4*)(hs + (size_t)s2 * D + col);
        a3 += *(const f4*)(hs + (size_t)s3 * D + col);
        a4 += *(const f4*)(hs + (size_t)s4 * D + col);
        a5 += *(const f4*)(hs + (size_t)s5 * D + col);
        a6 += *(const f4*)(hs + (size_t)s6 * D + col);
        a7 += *(const f4*)(hs + (size_t)s7 * D + col);
    }
    for (; e < end; e += 2)
        a0 += *(const f4*)(hs + (size_t)csr_src[e] * D + col);
    a0 += a1; a2 += a3; a4 += a5; a6 += a7;
    a0 += a2; a4 += a6;
    a0 += a4;

    f4 o;
#pragma unroll
    for (int j = 0; j < 4; ++j)
        o[j] = a0[j] + __shfl_xor(a0[j], 32, 64);
    if (grp == 0)
        *(f4*)(agg + (size_t)node * D + col) = o;
}

// --- out[r, cb*64 + :64] = relu(norm_dst[r]*(A[r] @ W[:, cb*64:+64]) + b) * post ---
// block: 256 threads, 256 rows x 64 cols; thread: 8 rows x 8 cols (two f4).
// A is padded to N_PAD rows -> unguarded contiguous loads (base + imm offsets).
__global__ __launch_bounds__(256, 2) void gemm_kernel(
    const float* __restrict__ A, const float* __restrict__ W,
    const float* __restrict__ bias, const float* __restrict__ norm_dst,
    const float* __restrict__ post, float* __restrict__ out) {
    __shared__ float Wl[D * 64];  // 32 KB
    int tid = threadIdx.x;
    int cb = blockIdx.y;          // column half: cols [cb*64, cb*64+64)
#pragma unroll
    for (int it = 0; it < 8; ++it) {
        int i = tid + it * 256;   // f4 index into Wl
        int k = i >> 4;
        int c4 = i & 15;
        *(f4*)(Wl + i * 4) = *(const f4*)(W + (size_t)k * D + cb * 64 + c4 * 4);
    }
    __syncthreads();

    int tx = tid & 7;             // 8 col groups
    int ty = tid >> 3;            // 32 row groups of 8
    int c = tx * 4;               // first f4 col (second at c+32)
    int row0 = blockIdx.x * 256 + ty * 8;
    const float* Abase = A + (size_t)row0 * D;

    f4 acc0[8], acc1[8];
#pragma unroll
    for (int r = 0; r < 8; ++r) { acc0[r] = (f4)0.0f; acc1[r] = (f4)0.0f; }

    for (int k4 = 0; k4 < D / 4; ++k4) {
        f4 a[8];
#pragma unroll
        for (int r = 0; r < 8; ++r)
            a[r] = *(const f4*)(Abase + r * D + k4 * 4);
#pragma unroll
        for (int kk = 0; kk < 4; ++kk) {
            int k = k4 * 4 + kk;
            f4 w0 = *(const f4*)(Wl + k * 64 + c);
            f4 w1 = *(const f4*)(Wl + k * 64 + c + 32);
#pragma unroll
            for (int r = 0; r < 8; ++r) {
                float av = a[r][kk];
                acc0[r] += av * w0;
                acc1[r] += av * w1;
            }
        }
    }

    f4 b0 = *(const f4*)(bias + cb * 64 + c);
    f4 b1 = *(const f4*)(bias + cb * 64 + c + 32);
#pragma unroll
    for (int r = 0; r < 8; ++r) {
        int row = row0 + r;
        if (row >= N) continue;
        float nd = norm_dst[row];
        float p = post ? post[row] : 1.0f;
        f4 o0 = acc0[r] * nd + b0;
        f4 o1 = acc1[r] * nd + b1;
#pragma unroll
        for (int j = 0; j < 4; ++j) {
            o0[j] = fmaxf(o0[j], 0.0f) * p;
            o1[j] = fmaxf(o1[j], 0.0f) * p;
        }
        *(f4*)(out + (size_t)row * D + cb * 64 + c) = o0;
        *(f4*)(out + (size_t)row * D + cb * 64 + c + 32) = o1;
    }
}

extern "C" void kernel_launch(void* const* d_in, const int* in_sizes, int n_in,
                              void* d_out, int out_size, void* d_ws, size_t ws_size,
                              hipStream_t stream) {
    const int*   batch = (const int*)d_in[0];
    const int*   src   = (const int*)d_in[1];
    const int*   dst   = (const int*)d_in[2];
    const float* emb   = (const float*)d_in[3];
    const float* W1    = (const float*)d_in[4];
    const float* b1    = (const float*)d_in[5];
    const float* W2    = (const float*)d_in[6];
    const float* b2    = (const float*)d_in[7];
    const float* W3    = (const float*)d_in[8];
    const float* b3    = (const float*)d_in[9];
    float* out = (float*)d_out;

    // ws layout (4B elems): norm_src[N] | norm_dst[N] | row_ptr[N+1] | csr_src[E]
    //                       | hs[N_PAD*D] | agg[N_PAD*D]
    // transient ints (deg_out, deg_in, cursor, bsums) alias the agg region.
    float* norm_src = (float*)d_ws;
    float* norm_dst = norm_src + N;
    int*   row_ptr  = (int*)(norm_dst + N);
    int*   csr_src  = row_ptr + (N + 1);
    float* hs       = (float*)(csr_src + E) + 3;  // 16B alignment
    float* agg      = hs + (size_t)N_PAD * D;
    int*   deg_out  = (int*)agg;   // transient
    int*   deg_in   = deg_out + N;
    int*   cursor   = deg_in + N;
    int*   bsums    = cursor + N;

    hipMemsetAsync(deg_out, 0, 3 * (size_t)N * sizeof(int), stream);
    deg_kernel<<<(E + 255) / 256, 256, 0, stream>>>(src, dst, deg_out, deg_in);
    norm_kernel<<<(N + 255) / 256, 256, 0, stream>>>(deg_out, deg_in, norm_src, norm_dst);
    scan_bsum_kernel<<<SCAN_NB, 256, 0, stream>>>(deg_in, bsums);
    scan_bsums_kernel<<<1, 256, 0, stream>>>(bsums);
    scan_final_kernel<<<SCAN_NB, 256, 0, stream>>>(deg_in, bsums, row_ptr);
    fill_kernel<<<(E + 255) / 256, 256, 0, stream>>>(src, dst, row_ptr, cursor, csr_src);
    gather_kernel<<<((size_t)N * 32 + 255) / 256, 256, 0, stream>>>(batch, emb, norm_src, hs);

    const float* Ws[3] = {W1, W2, W3};
    const float* bs[3] = {b1, b2, b3};
    dim3 ggrid(GEMM_RB, 2);
    for (int l = 0; l < 3; ++l) {
        bool last = (l == 2);
        agg_kernel<<<((size_t)N * 64 + 255) / 256, 256, 0, stream>>>(row_ptr, csr_src, hs, agg);
        gemm_kernel<<<ggrid, 256, 0, stream>>>(
            agg, Ws[l], bs[l], norm_dst,
            last ? nullptr : norm_src,
            last ? out : hs);
    }
}

// Round 6
// 394.191 us; speedup vs baseline: 10.8566x; 1.2401x over previous
//
#include <hip/hip_runtime.h>
#include <math.h>

typedef float f4 __attribute__((ext_vector_type(4)));
typedef float f32x4 __attribute__((ext_vector_type(4)));
typedef short s8 __attribute__((ext_vector_type(8)));  // 8 bf16 (4 VGPRs)

static constexpr int N = 50000;
static constexpr int E = 800000;
static constexpr int D = 128;
static constexpr int SCAN_NB = (N + 255) / 256;        // 196
static constexpr int MBLK = 64;                        // gemm rows/block
static constexpr int GRID_M = (N + MBLK - 1) / MBLK;   // 782
static constexpr int N_PAD = GRID_M * MBLK;            // 50048
static constexpr int WT_PITCH = 136;                   // LDS pad: 272 B rows, 16B-aligned

__device__ inline unsigned short f32_bf16_rne(float x) {
    unsigned u = __float_as_uint(x);
    return (unsigned short)((u + 0x7FFF + ((u >> 16) & 1)) >> 16);
}
__device__ inline float bf16_f32(unsigned short h) {
    return __uint_as_float((unsigned)h << 16);
}

// --- int degree histogram ---
__global__ void deg_kernel(const int* __restrict__ src, const int* __restrict__ dst,
                           int* __restrict__ deg_out, int* __restrict__ deg_in) {
    int e = blockIdx.x * 256 + threadIdx.x;
    if (e < E) {
        atomicAdd(&deg_out[src[e]], 1);
        atomicAdd(&deg_in[dst[e]], 1);
    }
}

// --- norms from int degrees ---
__global__ void norm_kernel(const int* __restrict__ deg_out, const int* __restrict__ deg_in,
                            float* __restrict__ norm_src, float* __restrict__ norm_dst) {
    int i = blockIdx.x * 256 + threadIdx.x;
    if (i < N) {
        norm_src[i] = rsqrtf(fmaxf((float)deg_out[i], 1.0f));
        norm_dst[i] = rsqrtf(fmaxf((float)deg_in[i], 1.0f));
    }
}

// --- scan pass 1: per-block sums ---
__global__ __launch_bounds__(256) void scan_bsum_kernel(const int* __restrict__ deg,
                                                        int* __restrict__ bsums) {
    int i = blockIdx.x * 256 + threadIdx.x;
    int v = (i < N) ? deg[i] : 0;
#pragma unroll
    for (int off = 1; off < 64; off <<= 1) v += __shfl_xor(v, off, 64);
    __shared__ int ws[4];
    if ((threadIdx.x & 63) == 0) ws[threadIdx.x >> 6] = v;
    __syncthreads();
    if (threadIdx.x == 0) bsums[blockIdx.x] = ws[0] + ws[1] + ws[2] + ws[3];
}

// --- scan pass 2: exclusive scan of block sums ---
__global__ __launch_bounds__(256) void scan_bsums_kernel(int* __restrict__ bsums) {
    __shared__ int s[256];
    int t = threadIdx.x;
    s[t] = (t < SCAN_NB) ? bsums[t] : 0;
    __syncthreads();
    for (int off = 1; off < 256; off <<= 1) {
        int v = (t >= off) ? s[t - off] : 0;
        __syncthreads();
        s[t] += v;
        __syncthreads();
    }
    if (t < SCAN_NB) bsums[t] = (t == 0) ? 0 : s[t - 1];
}

// --- scan pass 3: rescan + offset -> row_ptr ---
__global__ __launch_bounds__(256) void scan_final_kernel(const int* __restrict__ deg,
                                                         const int* __restrict__ bsums,
                                                         int* __restrict__ row_ptr) {
    __shared__ int s[256];
    int b = blockIdx.x, t = threadIdx.x;
    int i = b * 256 + t;
    s[t] = (i < N) ? deg[i] : 0;
    __syncthreads();
    for (int off = 1; off < 256; off <<= 1) {
        int v = (t >= off) ? s[t - off] : 0;
        __syncthreads();
        s[t] += v;
        __syncthreads();
    }
    if (i < N) row_ptr[i + 1] = s[t] + bsums[b];
    if (i == 0) row_ptr[0] = 0;
}

// --- csr_src fill ---
__global__ void fill_kernel(const int* __restrict__ src, const int* __restrict__ dst,
                            const int* __restrict__ row_ptr, int* __restrict__ cursor,
                            int* __restrict__ csr_src) {
    int e = blockIdx.x * 256 + threadIdx.x;
    if (e < E) {
        int d = dst[e];
        int pos = row_ptr[d] + atomicAdd(&cursor[d], 1);
        csr_src[pos] = src[e];
    }
}

// --- hs[i] = emb[batch[i]] * norm_src[i] ---
__global__ void gather_kernel(const int* __restrict__ batch, const float* __restrict__ emb,
                              const float* __restrict__ norm_src, float* __restrict__ hs) {
    int gid = blockIdx.x * 256 + threadIdx.x;
    int i = gid >> 5;
    int c = (gid & 31) << 2;
    if (i < N) {
        float s = norm_src[i];
        f4 v = *(const f4*)(emb + (size_t)batch[i] * D + c);
        *(f4*)(hs + (size_t)i * D + c) = v * s;
    }
}

// --- agg[n] = sum of hs[src]; 1 wave/node, 2 edge-groups x 8-deep unroll ---
__global__ void agg_kernel(const int* __restrict__ row_ptr, const int* __restrict__ csr_src,
                           const float* __restrict__ hs, float* __restrict__ agg) {
    int gid = blockIdx.x * 256 + threadIdx.x;
    int node = gid >> 6;
    if (node >= N) return;
    int lane = threadIdx.x & 63;
    int grp = lane >> 5;
    int col = (lane & 31) << 2;
    int beg = row_ptr[node], end = row_ptr[node + 1];

    f4 a0 = (f4)0.0f, a1 = (f4)0.0f, a2 = (f4)0.0f, a3 = (f4)0.0f;
    f4 a4 = (f4)0.0f, a5 = (f4)0.0f, a6 = (f4)0.0f, a7 = (f4)0.0f;
    int e = beg + grp;
    for (; e + 14 < end; e += 16) {
        int s0 = csr_src[e];
        int s1 = csr_src[e + 2];
        int s2 = csr_src[e + 4];
        int s3 = csr_src[e + 6];
        int s4 = csr_src[e + 8];
        int s5 = csr_src[e + 10];
        int s6 = csr_src[e + 12];
        int s7 = csr_src[e + 14];
        a0 += *(const f4*)(hs + (size_t)s0 * D + col);
        a1 += *(const f4*)(hs + (size_t)s1 * D + col);
        a2 += *(const f4*)(hs + (size_t)s2 * D + col);
        a3 += *(const f4*)(hs + (size_t)s3 * D + col);
        a4 += *(const f4*)(hs + (size_t)s4 * D + col);
        a5 += *(const f4*)(hs + (size_t)s5 * D + col);
        a6 += *(const f4*)(hs + (size_t)s6 * D + col);
        a7 += *(const f4*)(hs + (size_t)s7 * D + col);
    }
    for (; e < end; e += 2)
        a0 += *(const f4*)(hs + (size_t)csr_src[e] * D + col);
    a0 += a1; a2 += a3; a4 += a5; a6 += a7;
    a0 += a2; a4 += a6;
    a0 += a4;

    f4 o;
#pragma unroll
    for (int j = 0; j < 4; ++j)
        o[j] = a0[j] + __shfl_xor(a0[j], 32, 64);
    if (grp == 0)
        *(f4*)(agg + (size_t)node * D + col) = o;
}

// --- W prep: wt[layer][hi/lo][n][k] = bf16 split of W[k][n] (transposed, n-major) ---
__global__ void wprep_kernel(const float* __restrict__ W1, const float* __restrict__ W2,
                             const float* __restrict__ W3, short* __restrict__ wt) {
    int idx = blockIdx.x * 256 + threadIdx.x;
    if (idx >= 3 * D * D) return;
    int l = idx >> 14;          // layer
    int e = idx & (D * D - 1);
    int n = e >> 7, k = e & 127;
    const float* W = (l == 0) ? W1 : ((l == 1) ? W2 : W3);
    float w = W[(size_t)k * D + n];
    unsigned short h = f32_bf16_rne(w);
    unsigned short lo = f32_bf16_rne(w - bf16_f32(h));
    wt[(size_t)l * 2 * D * D + (size_t)n * D + k] = (short)h;
    wt[(size_t)l * 2 * D * D + D * D + (size_t)n * D + k] = (short)lo;
}

// --- MFMA GEMM: out[r, cb*64+:64] = relu(nd[r]*(A[r]@W[:,cols]) + b) * post[r]
// block: 256 thr = 4 waves; wave w: rows [blk*64 + w*16, +16), all 64 cols.
// A fp32 from global, split to bf16 hi/lo in regs; W staged hi/lo bf16 in LDS.
// 3-term split: C = Ah@Wh + Al@Wh + Ah@Wl  (error ~2^-18 rel).
__global__ __launch_bounds__(256, 2) void gemm_mfma_kernel(
    const float* __restrict__ A, const short* __restrict__ wth,
    const float* __restrict__ bias, const float* __restrict__ norm_dst,
    const float* __restrict__ post, float* __restrict__ out) {
    __shared__ short wt_h[64 * WT_PITCH];
    __shared__ short wt_l[64 * WT_PITCH];

    int tid = threadIdx.x;
    int cb = blockIdx.y;                        // column half
    const short* gh = wth + (size_t)cb * 64 * D;          // hi rows [cb*64, +64)
    const short* gl = wth + (size_t)D * D + (size_t)cb * 64 * D;

    // stage W half (64 n-rows x 128 k) hi+lo into padded LDS
#pragma unroll
    for (int it = 0; it < 4; ++it) {
        int c = tid + it * 256;                 // chunk of 8 shorts (1024 chunks)
        int n = c >> 4, kc = c & 15;
        *(s8*)(&wt_h[n * WT_PITCH + kc * 8]) = *(const s8*)(gh + (size_t)n * D + kc * 8);
        *(s8*)(&wt_l[n * WT_PITCH + kc * 8]) = *(const s8*)(gl + (size_t)n * D + kc * 8);
    }
    __syncthreads();

    int wv = tid >> 6;
    int lane = tid & 63;
    int lg = lane >> 4;                         // lane group 0..3 (k-slice)
    int lr = lane & 15;                         // row/col within 16-tile

    int arow = blockIdx.x * 64 + wv * 16 + lr;  // A row for this lane's fragments
    const float* abase = A + (size_t)arow * D;

    f32x4 acc[4];
#pragma unroll
    for (int nt = 0; nt < 4; ++nt) acc[nt] = (f32x4)0.0f;

#pragma unroll
    for (int kt = 0; kt < 4; ++kt) {
        // A fragment: 8 fp32 at k = kt*32 + lg*8, split to bf16 hi/lo
        const f4* ap = (const f4*)(abase + kt * 32 + lg * 8);
        f4 x0 = ap[0], x1 = ap[1];
        s8 ah, al;
#pragma unroll
        for (int i = 0; i < 8; ++i) {
            float x = (i < 4) ? x0[i] : x1[i - 4];
            unsigned short h = f32_bf16_rne(x);
            unsigned short lo = f32_bf16_rne(x - bf16_f32(h));
            ah[i] = (short)h;
            al[i] = (short)lo;
        }
#pragma unroll
        for (int nt = 0; nt < 4; ++nt) {
            int bidx = (nt * 16 + lr) * WT_PITCH + kt * 32 + lg * 8;
            s8 bh = *(const s8*)(&wt_h[bidx]);
            s8 bl = *(const s8*)(&wt_l[bidx]);
            acc[nt] = __builtin_amdgcn_mfma_f32_16x16x32_bf16(ah, bh, acc[nt], 0, 0, 0);
            acc[nt] = __builtin_amdgcn_mfma_f32_16x16x32_bf16(al, bh, acc[nt], 0, 0, 0);
            acc[nt] = __builtin_amdgcn_mfma_f32_16x16x32_bf16(ah, bl, acc[nt], 0, 0, 0);
        }
    }

    // epilogue: C[row = wv*16 + lg*4 + i][col = nt*16 + lr]
    int r0 = blockIdx.x * 64 + wv * 16 + lg * 4;
    float nd[4], ps[4];
#pragma unroll
    for (int i = 0; i < 4; ++i) {
        int gr = r0 + i;
        nd[i] = (gr < N) ? norm_dst[gr] : 0.0f;
        ps[i] = (gr < N) ? (post ? post[gr] : 1.0f) : 0.0f;
    }
#pragma unroll
    for (int nt = 0; nt < 4; ++nt) {
        int col = cb * 64 + nt * 16 + lr;
        float bv = bias[col];
#pragma unroll
        for (int i = 0; i < 4; ++i) {
            int gr = r0 + i;
            if (gr < N) {
                float v = fmaxf(acc[nt][i] * nd[i] + bv, 0.0f) * ps[i];
                out[(size_t)gr * D + col] = v;
            }
        }
    }
}

extern "C" void kernel_launch(void* const* d_in, const int* in_sizes, int n_in,
                              void* d_out, int out_size, void* d_ws, size_t ws_size,
                              hipStream_t stream) {
    const int*   batch = (const int*)d_in[0];
    const int*   src   = (const int*)d_in[1];
    const int*   dst   = (const int*)d_in[2];
    const float* emb   = (const float*)d_in[3];
    const float* W1    = (const float*)d_in[4];
    const float* b1    = (const float*)d_in[5];
    const float* W2    = (const float*)d_in[6];
    const float* b2    = (const float*)d_in[7];
    const float* W3    = (const float*)d_in[8];
    const float* b3    = (const float*)d_in[9];
    float* out = (float*)d_out;

    // ws layout (4B elems): norm_src[N] | norm_dst[N] | row_ptr[N+1] | csr_src[E]
    //                       | hs[N_PAD*D] | agg[N_PAD*D] | wt (3*2*D*D shorts)
    // transient ints (deg_out, deg_in, cursor, bsums) alias the agg region.
    float* norm_src = (float*)d_ws;
    float* norm_dst = norm_src + N;
    int*   row_ptr  = (int*)(norm_dst + N);
    int*   csr_src  = row_ptr + (N + 1);
    float* hs       = (float*)(csr_src + E) + 3;  // 16B alignment
    float* agg      = hs + (size_t)N_PAD * D;
    short* wt       = (short*)(agg + (size_t)N_PAD * D);
    int*   deg_out  = (int*)agg;   // transient
    int*   deg_in   = deg_out + N;
    int*   cursor   = deg_in + N;
    int*   bsums    = cursor + N;

    hipMemsetAsync(deg_out, 0, 3 * (size_t)N * sizeof(int), stream);
    deg_kernel<<<(E + 255) / 256, 256, 0, stream>>>(src, dst, deg_out, deg_in);
    norm_kernel<<<(N + 255) / 256, 256, 0, stream>>>(deg_out, deg_in, norm_src, norm_dst);
    scan_bsum_kernel<<<SCAN_NB, 256, 0, stream>>>(deg_in, bsums);
    scan_bsums_kernel<<<1, 256, 0, stream>>>(bsums);
    scan_final_kernel<<<SCAN_NB, 256, 0, stream>>>(deg_in, bsums, row_ptr);
    fill_kernel<<<(E + 255) / 256, 256, 0, stream>>>(src, dst, row_ptr, cursor, csr_src);
    gather_kernel<<<((size_t)N * 32 + 255) / 256, 256, 0, stream>>>(batch, emb, norm_src, hs);
    wprep_kernel<<<(3 * D * D + 255) / 256, 256, 0, stream>>>(W1, W2, W3, wt);

    const float* bs[3] = {b1, b2, b3};
    dim3 ggrid(GRID_M, 2);
    for (int l = 0; l < 3; ++l) {
        bool last = (l == 2);
        agg_kernel<<<((size_t)N * 64 + 255) / 256, 256, 0, stream>>>(row_ptr, csr_src, hs, agg);
        gemm_mfma_kernel<<<ggrid, 256, 0, stream>>>(
            agg, wt + (size_t)l * 2 * D * D, bs[l], norm_dst,
            last ? nullptr : norm_src,
            last ? out : hs);
    }
}